// Round 9
// baseline (233.742 us; speedup 1.0000x reference)
//
#include <hip/hip_runtime.h>
#include <hip/hip_bf16.h>
#include <stdint.h>

typedef unsigned short u16;
typedef __attribute__((ext_vector_type(8))) short short8;
typedef __attribute__((ext_vector_type(4))) float float4_;

#define N_B   2
#define L_SEQ 2048
#define H_N   16
#define D_H   64
#define EMB   1024
#define KWORDS (L_SEQ/64)   // 32

// log2(e)/32  (reference: softmax(scores/sqrt(1024))); folded into Q fragment
#define C2 0.045084220027780106f

// ws layout (bytes) -- total 27 MiB
#define KP_OFF 0u                      // K projected  [n][h][L][64] bf16 (8 MiB)
#define VP_OFF (8u*1024u*1024u)        // V projected TRANSPOSED [n][h][64][L] bf16 (8 MiB)
#define X2_OFF (16u*1024u*1024u)       // attention output [n][l][EMB] bf16 (8 MiB)
#define MP_OFF (24u*1024u*1024u)       // packed mask bits (1 MiB)
#define WB_OFF (25u*1024u*1024u)       // Wout bf16 (2 MiB)

// prep kernel role boundaries (blocks of 256 threads)
#define PREP_MASK  2048u                         // grid-stride: 64 words/block
#define PREP_CVTW  (PREP_MASK + 512u)
#define PREP_PROJK (PREP_CVTW + 1024u)
#define PREP_TOTAL (PREP_PROJK + 1024u)          // 4608

__device__ __forceinline__ u16 f2bf(float f) {
    __hip_bfloat16 h = __float2bfloat16(f);
    return *reinterpret_cast<u16*>(&h);
}
__device__ __forceinline__ short8 load8f(const float* p) {
    float4_ a = *(const float4_*)p;
    float4_ b = *(const float4_*)(p + 4);
    short8 r;
    r[0] = (short)f2bf(a[0]); r[1] = (short)f2bf(a[1]);
    r[2] = (short)f2bf(a[2]); r[3] = (short)f2bf(a[3]);
    r[4] = (short)f2bf(b[0]); r[5] = (short)f2bf(b[1]);
    r[6] = (short)f2bf(b[2]); r[7] = (short)f2bf(b[3]);
    return r;
}
__device__ __forceinline__ void gload16(const void* g, void* l) {
    __builtin_amdgcn_global_load_lds(
        (const __attribute__((address_space(1))) uint32_t*)(size_t)g,
        (__attribute__((address_space(3))) uint32_t*)(size_t)l, 16, 0, 0);
}
// pack two fp32 -> packed bf16 pair (lo=a, hi=b)
__device__ __forceinline__ uint32_t cvtpk(float a, float b) {
    uint32_t r;
    asm("v_cvt_pk_bf16_f32 %0, %1, %2" : "=v"(r) : "v"(a), "v"(b));
    return r;
}
// single-instruction 2^x (args bounded; no denormal guard needed)
__device__ __forceinline__ float fexp2(float x) {
    float r;
    asm("v_exp_f32 %0, %1" : "=v"(r) : "v"(x));
    return r;
}

// ---------------- K0: fused prep (maskpack | Wout cvt | K proj | V^T proj) ---
__global__ __launch_bounds__(256) void prep_kernel(const int* __restrict__ mask,
                                                   unsigned long long* __restrict__ mp,
                                                   const float* __restrict__ Wout,
                                                   u16* __restrict__ wb,
                                                   const float* __restrict__ keys,
                                                   const float* __restrict__ Wk,
                                                   u16* __restrict__ kp,
                                                   const float* __restrict__ values,
                                                   const float* __restrict__ Wv,
                                                   u16* __restrict__ vpT) {
    unsigned bid = blockIdx.x;
    int tid = threadIdx.x;

    if (bid < PREP_MASK) {
        int lane = tid & 63;
        int wv   = tid >> 6;
        for (int j = 0; j < 16; j++) {
            int wid = bid * 64 + j * 4 + wv;
            int m = mask[(size_t)wid * 64 + lane];
            unsigned long long bits = __ballot(m != 0);
            if (lane == 0) mp[wid] = bits;
        }
        return;
    }
    if (bid < PREP_CVTW) {
        int i = ((bid - PREP_MASK) * 256 + tid) * 8;
        *(short8*)(wb + i) = load8f(Wout + i);
        return;
    }

    bool isK = bid < PREP_PROJK;
    unsigned lb = bid - (isK ? PREP_CVTW : PREP_PROJK);
    const float* x = isK ? keys : values;
    const float* W = isK ? Wk : Wv;

    int lt = lb & 31;
    int h  = (lb >> 5) & 15;
    int n  = lb >> 9;
    int w = tid >> 6, lane = tid & 63;
    int g = lane >> 4, r16 = lane & 15;
    int l0 = lt * 64 + w * 16;

    const float* xrow = x + ((size_t)(n * L_SEQ + l0 + r16)) * EMB + h * 64;
    short8 a0 = load8f(xrow + 8 * g);
    short8 a1 = load8f(xrow + 32 + 8 * g);

    short8 wf[4][2];
    for (int eb = 0; eb < 4; eb++)
        for (int ch = 0; ch < 2; ch++)
            wf[eb][ch] = load8f(W + (eb * 16 + r16) * 64 + ch * 32 + 8 * g);

    if (isK) {
        u16* ob = kp + ((size_t)((n * H_N + h) * L_SEQ + l0)) * 64;
        for (int eb = 0; eb < 4; eb++) {
            float4_ c = {0.f, 0.f, 0.f, 0.f};
            c = __builtin_amdgcn_mfma_f32_16x16x32_bf16(a0, wf[eb][0], c, 0, 0, 0);
            c = __builtin_amdgcn_mfma_f32_16x16x32_bf16(a1, wf[eb][1], c, 0, 0, 0);
            for (int i = 0; i < 4; i++)
                ob[(size_t)(4 * g + i) * 64 + eb * 16 + r16] = f2bf(c[i]);
        }
    } else {
        u16* obase = vpT + ((size_t)(n * H_N + h)) * (64 * L_SEQ) + l0 + r16;
        for (int eb = 0; eb < 4; eb++) {
            float4_ c = {0.f, 0.f, 0.f, 0.f};
            c = __builtin_amdgcn_mfma_f32_16x16x32_bf16(wf[eb][0], a0, c, 0, 0, 0);
            c = __builtin_amdgcn_mfma_f32_16x16x32_bf16(wf[eb][1], a1, c, 0, 0, 0);
            for (int i = 0; i < 4; i++)
                obase[(size_t)(eb * 16 + 4 * g + i) * L_SEQ] = f2bf(c[i]);
        }
    }
}

// ---------------- K2: flash attention, 2 q-subtiles/wave + counted-vmcnt dbuf -
// Block = 4 waves x (16+16) q-rows = 128 q-rows, grid 512. K/V LDS fragments
// read once, used for both subtiles (halves LDS-pipe bytes per unit work).
// VMEM issue order per kt: [mask words][STAGE kt+1] then vmcnt(6): guarantees
// stage(kt) complete, leaves words+stage(kt+1) in flight through compute.
__global__ __launch_bounds__(256) void attn_kernel(const float* __restrict__ query,
                                                   const float* __restrict__ Wq,
                                                   const u16* __restrict__ kp,
                                                   const u16* __restrict__ vpT,
                                                   const unsigned long long* __restrict__ mp,
                                                   u16* __restrict__ x2) {
    __shared__ __align__(16) u16 Ks[2][64 * 64];       // K rows, swizzled content
    __shared__ __align__(16) u16 Vt[2][64 * 64];       // V^T rows, swizzled content
    __shared__ __align__(16) u16 Pt[4][2][16 * 64];    // per-wave, per-sub P^T

    int bid = blockIdx.x;
    int nh = bid & 31, qt = bid >> 5;   // same-nh blocks: stride 32 -> one XCD
    int n = nh >> 4;
    int h = nh & 15;
    int tid = threadIdx.x;
    int w = tid >> 6, lane = tid & 63;
    int g = lane >> 4, r16 = lane & 15;
    int q0 = qt * 128 + w * 16;          // sub0 rows [q0,q0+16), sub1 +64

    const u16* kb  = kp  + ((size_t)nh * L_SEQ) * 64;
    const u16* vtb = vpT + ((size_t)nh) * (64 * L_SEQ);

    int psw = (r16 & 7) << 4;

    // staging: lane covers one 16B chunk; pre-swizzled source, linear LDS dest
    int rs = (w << 3) + (lane >> 3);              // row 0..31 (+32 for half 1)
    int cc = (lane & 7) ^ ((lane >> 3) & 7);

    #define STAGE(kt_, b_) do {                                                  \
        int k0_ = (kt_) * 64;                                                    \
        for (int h2 = 0; h2 < 2; h2++) {                                         \
            int r_ = rs + 32 * h2;                                               \
            gload16(kb  + (size_t)(k0_ + r_) * 64 + cc * 8,                      \
                    (char*)Ks[b_] + w * 1024 + h2 * 4096);                       \
            gload16(vtb + (size_t)r_ * L_SEQ + k0_ + cc * 8,                     \
                    (char*)Vt[b_] + w * 1024 + h2 * 4096);                       \
        }                                                                        \
    } while (0)

    STAGE(0, 0);   // prefetch tile 0 under Q-projection

    // ---- Q projection for both subs (Wq fragments loaded once); Q *= C2 ----
    short8 wf[4][2];
    for (int eb = 0; eb < 4; eb++)
        for (int ch = 0; ch < 2; ch++)
            wf[eb][ch] = load8f(Wq + (eb * 16 + r16) * 64 + ch * 32 + 8 * g);

    for (int s = 0; s < 2; s++) {
        const float* qrow = query + ((size_t)(n * L_SEQ + q0 + s * 64 + r16)) * EMB + h * 64;
        short8 a0 = load8f(qrow + 8 * g);
        short8 a1 = load8f(qrow + 32 + 8 * g);
        for (int eb = 0; eb < 4; eb++) {
            float4_ c = {0.f, 0.f, 0.f, 0.f};
            c = __builtin_amdgcn_mfma_f32_16x16x32_bf16(a0, wf[eb][0], c, 0, 0, 0);
            c = __builtin_amdgcn_mfma_f32_16x16x32_bf16(a1, wf[eb][1], c, 0, 0, 0);
            for (int i = 0; i < 4; i++) {
                int row = 4 * g + i;
                *(u16*)((char*)Pt[w][s] + row * 128 + (((eb * 16 + r16) * 2) ^ ((row & 7) << 4))) = f2bf(c[i] * C2);
            }
        }
    }
    short8 aq00 = *(const short8*)((char*)Pt[w][0] + r16 * 128 + ((16 * g) ^ psw));
    short8 aq01 = *(const short8*)((char*)Pt[w][0] + r16 * 128 + ((64 + 16 * g) ^ psw));
    short8 aq10 = *(const short8*)((char*)Pt[w][1] + r16 * 128 + ((16 * g) ^ psw));
    short8 aq11 = *(const short8*)((char*)Pt[w][1] + r16 * 128 + ((64 + 16 * g) ^ psw));

    float4_ o0[4] = {}, o1[4] = {};
    float lp0 = 0.f, lp1 = 0.f;
    const unsigned long long* mprow0 = mp + ((size_t)n * L_SEQ + q0 + r16) * KWORDS;
    const unsigned long long* mprow1 = mprow0 + (size_t)64 * KWORDS;

    int cur = 0;
    for (int kt = 0; kt < 32; kt++) {
        // words FIRST (older than next stage in the vmcnt queue)
        unsigned long long word0 = mprow0[kt];
        unsigned long long word1 = mprow1[kt];
        __builtin_amdgcn_sched_barrier(0);
        if (kt < 31) {
            STAGE(kt + 1, cur ^ 1);
            __builtin_amdgcn_sched_barrier(0);
            asm volatile("s_waitcnt vmcnt(6)" ::: "memory");  // stage(kt) done
        } else {
            asm volatile("s_waitcnt vmcnt(0)" ::: "memory");
        }
        __builtin_amdgcn_s_barrier();
        __builtin_amdgcn_sched_barrier(0);

        const char* ksb   = (const char*)Ks[cur];
        const char* vtbuf = (const char*)Vt[cur];

        __builtin_amdgcn_s_setprio(1);
        // S^T = mfma(A=K, B=Q*C2); K fragments read once, used for both subs
        for (int cb = 0; cb < 4; cb++) {
            int row = cb * 16 + r16;
            int sw = (row & 7) << 4;
            short8 bk0 = *(const short8*)(ksb + row * 128 + ((16 * g) ^ sw));
            short8 bk1 = *(const short8*)(ksb + row * 128 + ((64 + 16 * g) ^ sw));
            float4_ c0 = {0.f, 0.f, 0.f, 0.f};
            c0 = __builtin_amdgcn_mfma_f32_16x16x32_bf16(bk0, aq00, c0, 0, 0, 0);
            c0 = __builtin_amdgcn_mfma_f32_16x16x32_bf16(bk1, aq01, c0, 0, 0, 0);
            float4_ c1 = {0.f, 0.f, 0.f, 0.f};
            c1 = __builtin_amdgcn_mfma_f32_16x16x32_bf16(bk0, aq10, c1, 0, 0, 0);
            c1 = __builtin_amdgcn_mfma_f32_16x16x32_bf16(bk1, aq11, c1, 0, 0, 0);

            uint32_t nib0 = (uint32_t)(word0 >> (16 * cb + 4 * g)) & 0xFu;
            uint32_t nib1 = (uint32_t)(word1 >> (16 * cb + 4 * g)) & 0xFu;

            float p0 = (nib0 & 1u) ? fexp2(c0[0]) : 0.f;
            float p1 = (nib0 & 2u) ? fexp2(c0[1]) : 0.f;
            float p2 = (nib0 & 4u) ? fexp2(c0[2]) : 0.f;
            float p3 = (nib0 & 8u) ? fexp2(c0[3]) : 0.f;
            lp0 += (p0 + p1) + (p2 + p3);
            uint2 pk0; pk0.x = cvtpk(p0, p1); pk0.y = cvtpk(p2, p3);
            *(uint2*)((char*)Pt[w][0] + r16 * 128 + ((cb * 32 + 8 * g) ^ psw)) = pk0;

            float q0v = (nib1 & 1u) ? fexp2(c1[0]) : 0.f;
            float q1v = (nib1 & 2u) ? fexp2(c1[1]) : 0.f;
            float q2v = (nib1 & 4u) ? fexp2(c1[2]) : 0.f;
            float q3v = (nib1 & 8u) ? fexp2(c1[3]) : 0.f;
            lp1 += (q0v + q1v) + (q2v + q3v);
            uint2 pk1; pk1.x = cvtpk(q0v, q1v); pk1.y = cvtpk(q2v, q3v);
            *(uint2*)((char*)Pt[w][1] + r16 * 128 + ((cb * 32 + 8 * g) ^ psw)) = pk1;
        }

        short8 pb00 = *(const short8*)((char*)Pt[w][0] + r16 * 128 + ((16 * g) ^ psw));
        short8 pb01 = *(const short8*)((char*)Pt[w][0] + r16 * 128 + ((64 + 16 * g) ^ psw));
        short8 pb10 = *(const short8*)((char*)Pt[w][1] + r16 * 128 + ((16 * g) ^ psw));
        short8 pb11 = *(const short8*)((char*)Pt[w][1] + r16 * 128 + ((64 + 16 * g) ^ psw));

        // O^T += mfma(A=V^T, B=P); V fragments read once, used for both subs
        for (int db = 0; db < 4; db++) {
            int row = db * 16 + r16;
            int sw = (row & 7) << 4;
            short8 av0 = *(const short8*)(vtbuf + row * 128 + ((16 * g) ^ sw));
            short8 av1 = *(const short8*)(vtbuf + row * 128 + ((64 + 16 * g) ^ sw));
            o0[db] = __builtin_amdgcn_mfma_f32_16x16x32_bf16(av0, pb00, o0[db], 0, 0, 0);
            o0[db] = __builtin_amdgcn_mfma_f32_16x16x32_bf16(av1, pb01, o0[db], 0, 0, 0);
            o1[db] = __builtin_amdgcn_mfma_f32_16x16x32_bf16(av0, pb10, o1[db], 0, 0, 0);
            o1[db] = __builtin_amdgcn_mfma_f32_16x16x32_bf16(av1, pb11, o1[db], 0, 0, 0);
        }
        __builtin_amdgcn_s_setprio(0);

        __builtin_amdgcn_sched_barrier(0);
        __builtin_amdgcn_s_barrier();     // protect buf[cur] before next stage
        cur ^= 1;
    }
    #undef STAGE

    float t0 = lp0;
    t0 += __shfl_xor(t0, 16);
    t0 += __shfl_xor(t0, 32);
    float inv0 = 1.f / fmaxf(t0, 1e-30f);
    float t1 = lp1;
    t1 += __shfl_xor(t1, 16);
    t1 += __shfl_xor(t1, 32);
    float inv1 = 1.f / fmaxf(t1, 1e-30f);

    u16* ob0 = x2 + ((size_t)(n * L_SEQ + q0 + r16)) * EMB + h * 64;
    u16* ob1 = x2 + ((size_t)(n * L_SEQ + q0 + 64 + r16)) * EMB + h * 64;
    for (int db = 0; db < 4; db++)
        for (int i = 0; i < 4; i++) {
            ob0[db * 16 + 4 * g + i] = f2bf(o0[db][i] * inv0);
            ob1[db * 16 + 4 * g + i] = f2bf(o1[db][i] * inv1);
        }
}

// ---------------- K3: OUT = X2 @ Wout^T + bout, counted-vmcnt dbuf -----------
__global__ __launch_bounds__(512) void outgemm_kernel(const u16* __restrict__ x2,
                                                      const u16* __restrict__ Wb,
                                                      const float* __restrict__ bout,
                                                      float* __restrict__ out) {
    __shared__ __align__(16) u16 As[2][128 * 64];
    __shared__ __align__(16) u16 Bs[2][128 * 64];

    int bid = blockIdx.x;
    int mt = bid >> 3, nt = bid & 7;
    int m0 = mt * 128, n0 = nt * 128;
    int tid = threadIdx.x;
    int w = tid >> 6, lane = tid & 63;
    int g = lane >> 4, r16 = lane & 15;
    int wr = w >> 2, wc = w & 3;

    float4_ acc[4][2] = {};

    int rs = (w << 3) + (lane >> 3);        // row 0..63
    int cc = (lane & 7) ^ ((lane >> 3) & 7);

    #define OSTAGE(kb_, b_) do {                                                 \
        int kk_ = (kb_) * 64;                                                    \
        for (int h2 = 0; h2 < 2; h2++) {                                         \
            int r_ = rs + 64 * h2;                                               \
            gload16(x2 + (size_t)(m0 + r_) * EMB + kk_ + cc * 8,                 \
                    (char*)As[b_] + w * 1024 + h2 * 8192);                       \
            gload16(Wb + (size_t)(n0 + r_) * EMB + kk_ + cc * 8,                 \
                    (char*)Bs[b_] + w * 1024 + h2 * 8192);                       \
        }                                                                        \
    } while (0)

    OSTAGE(0, 0);
    int cur = 0;

    for (int kbk = 0; kbk < 16; kbk++) {
        if (kbk < 15) {
            OSTAGE(kbk + 1, cur ^ 1);
            __builtin_amdgcn_sched_barrier(0);
            asm volatile("s_waitcnt vmcnt(4)" ::: "memory");
        } else {
            asm volatile("s_waitcnt vmcnt(0)" ::: "memory");
        }
        __builtin_amdgcn_s_barrier();
        __builtin_amdgcn_sched_barrier(0);

        const char* pa = (const char*)As[cur];
        const char* pb = (const char*)Bs[cur];

        short8 afr[4][2], bfr[2][2];
        for (int sm = 0; sm < 4; sm++)
            for (int ch = 0; ch < 2; ch++) {
                int row = wr * 64 + sm * 16 + r16;
                afr[sm][ch] = *(const short8*)(pa + row * 128 + ((ch * 64 + 16 * g) ^ ((row & 7) << 4)));
            }
        for (int sn = 0; sn < 2; sn++)
            for (int ch = 0; ch < 2; ch++) {
                int row = wc * 32 + sn * 16 + r16;
                bfr[sn][ch] = *(const short8*)(pb + row * 128 + ((ch * 64 + 16 * g) ^ ((row & 7) << 4)));
            }
        __builtin_amdgcn_s_setprio(1);
        for (int sm = 0; sm < 4; sm++)
            for (int sn = 0; sn < 2; sn++) {
                acc[sm][sn] = __builtin_amdgcn_mfma_f32_16x16x32_bf16(afr[sm][0], bfr[sn][0], acc[sm][sn], 0, 0, 0);
                acc[sm][sn] = __builtin_amdgcn_mfma_f32_16x16x32_bf16(afr[sm][1], bfr[sn][1], acc[sm][sn], 0, 0, 0);
            }
        __builtin_amdgcn_s_setprio(0);

        __builtin_amdgcn_sched_barrier(0);
        __builtin_amdgcn_s_barrier();
        cur ^= 1;
    }
    #undef OSTAGE

    for (int sm = 0; sm < 4; sm++)
        for (int sn = 0; sn < 2; sn++) {
            int nn = n0 + wc * 32 + sn * 16 + r16;
            float bv = bout[nn];
            for (int i = 0; i < 4; i++) {
                int mm = m0 + wr * 64 + sm * 16 + 4 * g + i;
                out[(size_t)mm * EMB + nn] = acc[sm][sn][i] + bv;
            }
        }
}

extern "C" void kernel_launch(void* const* d_in, const int* in_sizes, int n_in,
                              void* d_out, int out_size, void* d_ws, size_t ws_size,
                              hipStream_t stream) {
    const float* values = (const float*)d_in[0];
    const float* keys   = (const float*)d_in[1];
    const float* query  = (const float*)d_in[2];
    const int*   mask   = (const int*)d_in[3];
    const float* Wv     = (const float*)d_in[4];
    const float* Wk     = (const float*)d_in[5];
    const float* Wq     = (const float*)d_in[6];
    const float* Wout   = (const float*)d_in[7];
    const float* bout   = (const float*)d_in[8];
    float* out = (float*)d_out;

    char* ws = (char*)d_ws;
    u16* kp  = (u16*)(ws + KP_OFF);
    u16* vpT = (u16*)(ws + VP_OFF);
    u16* x2  = (u16*)(ws + X2_OFF);
    unsigned long long* mpk = (unsigned long long*)(ws + MP_OFF);
    u16* wb  = (u16*)(ws + WB_OFF);

    prep_kernel<<<PREP_TOTAL, 256, 0, stream>>>(mask, mpk, Wout, wb,
                                                keys, Wk, kp, values, Wv, vpT);
    attn_kernel<<<512, 256, 0, stream>>>(query, Wq, kp, vpT, mpk, x2);
    outgemm_kernel<<<256, 512, 0, stream>>>(x2, wb, bout, out);
}

// Round 10
// 230.093 us; speedup vs baseline: 1.0159x; 1.0159x over previous
//
#include <hip/hip_runtime.h>
#include <hip/hip_bf16.h>
#include <stdint.h>

typedef unsigned short u16;
typedef __attribute__((ext_vector_type(8))) short short8;
typedef __attribute__((ext_vector_type(4))) float float4_;

#define N_B   2
#define L_SEQ 2048
#define H_N   16
#define D_H   64
#define EMB   1024
#define KWORDS (L_SEQ/64)   // 32

// log2(e)/32  (reference: softmax(scores/sqrt(1024))); folded into Q fragment
#define C2 0.045084220027780106f

// ws layout (bytes) -- total 27 MiB
#define KP_OFF 0u                      // K projected  [n][h][L][64] bf16 (8 MiB)
#define VP_OFF (8u*1024u*1024u)        // V projected TRANSPOSED [n][h][64][L] bf16 (8 MiB)
#define X2_OFF (16u*1024u*1024u)       // attention output [n][l][EMB] bf16 (8 MiB)
#define MP_OFF (24u*1024u*1024u)       // packed mask bits (1 MiB)
#define WB_OFF (25u*1024u*1024u)       // Wout bf16 (2 MiB)

// prep kernel role boundaries (blocks of 256 threads)
#define PREP_MASK  2048u                         // grid-stride: 64 words/block
#define PREP_CVTW  (PREP_MASK + 512u)
#define PREP_PROJK (PREP_CVTW + 1024u)
#define PREP_TOTAL (PREP_PROJK + 1024u)          // 4608

__device__ __forceinline__ u16 f2bf(float f) {
    __hip_bfloat16 h = __float2bfloat16(f);
    return *reinterpret_cast<u16*>(&h);
}
__device__ __forceinline__ short8 load8f(const float* p) {
    float4_ a = *(const float4_*)p;
    float4_ b = *(const float4_*)(p + 4);
    short8 r;
    r[0] = (short)f2bf(a[0]); r[1] = (short)f2bf(a[1]);
    r[2] = (short)f2bf(a[2]); r[3] = (short)f2bf(a[3]);
    r[4] = (short)f2bf(b[0]); r[5] = (short)f2bf(b[1]);
    r[6] = (short)f2bf(b[2]); r[7] = (short)f2bf(b[3]);
    return r;
}
__device__ __forceinline__ void gload16(const void* g, void* l) {
    __builtin_amdgcn_global_load_lds(
        (const __attribute__((address_space(1))) uint32_t*)(size_t)g,
        (__attribute__((address_space(3))) uint32_t*)(size_t)l, 16, 0, 0);
}
// pack two fp32 -> packed bf16 pair (lo=a, hi=b)
__device__ __forceinline__ uint32_t cvtpk(float a, float b) {
    uint32_t r;
    asm("v_cvt_pk_bf16_f32 %0, %1, %2" : "=v"(r) : "v"(a), "v"(b));
    return r;
}
// single-instruction 2^x (args bounded; no denormal guard needed)
__device__ __forceinline__ float fexp2(float x) {
    float r;
    asm("v_exp_f32 %0, %1" : "=v"(r) : "v"(x));
    return r;
}

// ---------------- K0: fused prep (maskpack | Wout cvt | K proj | V^T proj) ---
__global__ __launch_bounds__(256) void prep_kernel(const int* __restrict__ mask,
                                                   unsigned long long* __restrict__ mp,
                                                   const float* __restrict__ Wout,
                                                   u16* __restrict__ wb,
                                                   const float* __restrict__ keys,
                                                   const float* __restrict__ Wk,
                                                   u16* __restrict__ kp,
                                                   const float* __restrict__ values,
                                                   const float* __restrict__ Wv,
                                                   u16* __restrict__ vpT) {
    unsigned bid = blockIdx.x;
    int tid = threadIdx.x;

    if (bid < PREP_MASK) {
        int lane = tid & 63;
        int wv   = tid >> 6;
        for (int j = 0; j < 16; j++) {
            int wid = bid * 64 + j * 4 + wv;
            int m = mask[(size_t)wid * 64 + lane];
            unsigned long long bits = __ballot(m != 0);
            if (lane == 0) mp[wid] = bits;
        }
        return;
    }
    if (bid < PREP_CVTW) {
        int i = ((bid - PREP_MASK) * 256 + tid) * 8;
        *(short8*)(wb + i) = load8f(Wout + i);
        return;
    }

    bool isK = bid < PREP_PROJK;
    unsigned lb = bid - (isK ? PREP_CVTW : PREP_PROJK);
    const float* x = isK ? keys : values;
    const float* W = isK ? Wk : Wv;

    int lt = lb & 31;
    int h  = (lb >> 5) & 15;
    int n  = lb >> 9;
    int w = tid >> 6, lane = tid & 63;
    int g = lane >> 4, r16 = lane & 15;
    int l0 = lt * 64 + w * 16;

    const float* xrow = x + ((size_t)(n * L_SEQ + l0 + r16)) * EMB + h * 64;
    short8 a0 = load8f(xrow + 8 * g);
    short8 a1 = load8f(xrow + 32 + 8 * g);

    short8 wf[4][2];
    for (int eb = 0; eb < 4; eb++)
        for (int ch = 0; ch < 2; ch++)
            wf[eb][ch] = load8f(W + (eb * 16 + r16) * 64 + ch * 32 + 8 * g);

    if (isK) {
        u16* ob = kp + ((size_t)((n * H_N + h) * L_SEQ + l0)) * 64;
        for (int eb = 0; eb < 4; eb++) {
            float4_ c = {0.f, 0.f, 0.f, 0.f};
            c = __builtin_amdgcn_mfma_f32_16x16x32_bf16(a0, wf[eb][0], c, 0, 0, 0);
            c = __builtin_amdgcn_mfma_f32_16x16x32_bf16(a1, wf[eb][1], c, 0, 0, 0);
            for (int i = 0; i < 4; i++)
                ob[(size_t)(4 * g + i) * 64 + eb * 16 + r16] = f2bf(c[i]);
        }
    } else {
        u16* obase = vpT + ((size_t)(n * H_N + h)) * (64 * L_SEQ) + l0 + r16;
        for (int eb = 0; eb < 4; eb++) {
            float4_ c = {0.f, 0.f, 0.f, 0.f};
            c = __builtin_amdgcn_mfma_f32_16x16x32_bf16(wf[eb][0], a0, c, 0, 0, 0);
            c = __builtin_amdgcn_mfma_f32_16x16x32_bf16(wf[eb][1], a1, c, 0, 0, 0);
            for (int i = 0; i < 4; i++)
                obase[(size_t)(eb * 16 + 4 * g + i) * L_SEQ] = f2bf(c[i]);
        }
    }
}

// ---------------- K2: flash attention per (n,h), round-8 structure -----------
// 64 q-rows/block, grid 1024 (4 blocks/CU). Double-buffered K/V via counted
// vmcnt. Per-kt VMEM issue order: [mask word][STAGE kt+1] -> vmcnt(5) waits
// only stage(kt); compiler's word-wait lands at vmcnt(4); stage(kt+1) stays
// in flight through compute.
__global__ __launch_bounds__(256) void attn_kernel(const float* __restrict__ query,
                                                   const float* __restrict__ Wq,
                                                   const u16* __restrict__ kp,
                                                   const u16* __restrict__ vpT,
                                                   const unsigned long long* __restrict__ mp,
                                                   u16* __restrict__ x2) {
    __shared__ __align__(16) u16 Ks[2][64 * 64];     // K rows, swizzled content
    __shared__ __align__(16) u16 Vt[2][64 * 64];     // V^T rows, swizzled content
    __shared__ __align__(16) u16 Pt[4][16 * 64];     // per-wave P^T (also Q staging)

    int bid = blockIdx.x;
    int nh = bid & 31, qt = bid >> 5;   // same-nh blocks: stride 32 -> one XCD
    int n = nh >> 4;
    int h = nh & 15;
    int tid = threadIdx.x;
    int w = tid >> 6, lane = tid & 63;
    int g = lane >> 4, r16 = lane & 15;
    int q0 = qt * 64 + w * 16;

    const u16* kb  = kp  + ((size_t)nh * L_SEQ) * 64;
    const u16* vtb = vpT + ((size_t)nh) * (64 * L_SEQ);

    int psw = (r16 & 7) << 4;

    // staging: lane covers one 16B chunk; pre-swizzled source, linear LDS dest
    int rs = (w << 3) + (lane >> 3);              // row 0..31 (+32 for half 1)
    int cc = (lane & 7) ^ ((lane >> 3) & 7);

    #define STAGE(kt_, b_) do {                                                  \
        int k0_ = (kt_) * 64;                                                    \
        for (int h2 = 0; h2 < 2; h2++) {                                         \
            int r_ = rs + 32 * h2;                                               \
            gload16(kb  + (size_t)(k0_ + r_) * 64 + cc * 8,                      \
                    (char*)Ks[b_] + w * 1024 + h2 * 4096);                       \
            gload16(vtb + (size_t)r_ * L_SEQ + k0_ + cc * 8,                     \
                    (char*)Vt[b_] + w * 1024 + h2 * 4096);                       \
        }                                                                        \
    } while (0)

    STAGE(0, 0);   // prefetch tile 0 under Q-projection

    // ---- in-block Q projection (wave-private, staged through Pt[w]); Q *= C2
    {
        const float* qrow = query + ((size_t)(n * L_SEQ + q0 + r16)) * EMB + h * 64;
        short8 a0 = load8f(qrow + 8 * g);
        short8 a1 = load8f(qrow + 32 + 8 * g);
        for (int eb = 0; eb < 4; eb++) {
            short8 w0 = load8f(Wq + (eb * 16 + r16) * 64 + 8 * g);
            short8 w1 = load8f(Wq + (eb * 16 + r16) * 64 + 32 + 8 * g);
            float4_ c = {0.f, 0.f, 0.f, 0.f};
            c = __builtin_amdgcn_mfma_f32_16x16x32_bf16(a0, w0, c, 0, 0, 0);
            c = __builtin_amdgcn_mfma_f32_16x16x32_bf16(a1, w1, c, 0, 0, 0);
            for (int i = 0; i < 4; i++) {
                int row = 4 * g + i;
                *(u16*)((char*)Pt[w] + row * 128 + (((eb * 16 + r16) * 2) ^ ((row & 7) << 4))) = f2bf(c[i] * C2);
            }
        }
    }
    short8 aq0 = *(const short8*)((char*)Pt[w] + r16 * 128 + ((16 * g) ^ psw));
    short8 aq1 = *(const short8*)((char*)Pt[w] + r16 * 128 + ((64 + 16 * g) ^ psw));

    float4_ o[4] = {};
    float lpart = 0.f;
    const unsigned long long* mprow = mp + ((size_t)n * L_SEQ + q0 + r16) * KWORDS;

    int cur = 0;
    for (int kt = 0; kt < 32; kt++) {
        // mask word FIRST (older than next stage in the vmcnt queue)
        unsigned long long word = mprow[kt];
        __builtin_amdgcn_sched_barrier(0);
        if (kt < 31) {
            STAGE(kt + 1, cur ^ 1);
            __builtin_amdgcn_sched_barrier(0);
            asm volatile("s_waitcnt vmcnt(5)" ::: "memory");  // stage(kt) done
        } else {
            asm volatile("s_waitcnt vmcnt(0)" ::: "memory");
        }
        __builtin_amdgcn_s_barrier();
        __builtin_amdgcn_sched_barrier(0);

        const char* ksb   = (const char*)Ks[cur];
        const char* vtbuf = (const char*)Vt[cur];

        __builtin_amdgcn_s_setprio(1);
        // S^T = mfma(A=K, B=Q*C2): lane holds S[q=r16][k=16cb+4g+i]
        for (int cb = 0; cb < 4; cb++) {
            int row = cb * 16 + r16;
            int sw = (row & 7) << 4;
            short8 bk0 = *(const short8*)(ksb + row * 128 + ((16 * g) ^ sw));
            short8 bk1 = *(const short8*)(ksb + row * 128 + ((64 + 16 * g) ^ sw));
            float4_ c = {0.f, 0.f, 0.f, 0.f};
            c = __builtin_amdgcn_mfma_f32_16x16x32_bf16(bk0, aq0, c, 0, 0, 0);
            c = __builtin_amdgcn_mfma_f32_16x16x32_bf16(bk1, aq1, c, 0, 0, 0);

            uint32_t nib = (uint32_t)(word >> (16 * cb + 4 * g)) & 0xFu;
            float p0 = (nib & 1u) ? fexp2(c[0]) : 0.f;
            float p1 = (nib & 2u) ? fexp2(c[1]) : 0.f;
            float p2 = (nib & 4u) ? fexp2(c[2]) : 0.f;
            float p3 = (nib & 8u) ? fexp2(c[3]) : 0.f;
            lpart += (p0 + p1) + (p2 + p3);
            uint2 pkv; pkv.x = cvtpk(p0, p1); pkv.y = cvtpk(p2, p3);
            *(uint2*)((char*)Pt[w] + r16 * 128 + ((cb * 32 + 8 * g) ^ psw)) = pkv;
        }

        // P fragment: P[q=r16][k=8g+j]
        short8 pb0 = *(const short8*)((char*)Pt[w] + r16 * 128 + ((16 * g) ^ psw));
        short8 pb1 = *(const short8*)((char*)Pt[w] + r16 * 128 + ((64 + 16 * g) ^ psw));

        // O^T += mfma(A=V^T, B=P)
        for (int db = 0; db < 4; db++) {
            int row = db * 16 + r16;
            int sw = (row & 7) << 4;
            short8 av0 = *(const short8*)(vtbuf + row * 128 + ((16 * g) ^ sw));
            short8 av1 = *(const short8*)(vtbuf + row * 128 + ((64 + 16 * g) ^ sw));
            o[db] = __builtin_amdgcn_mfma_f32_16x16x32_bf16(av0, pb0, o[db], 0, 0, 0);
            o[db] = __builtin_amdgcn_mfma_f32_16x16x32_bf16(av1, pb1, o[db], 0, 0, 0);
        }
        __builtin_amdgcn_s_setprio(0);

        __builtin_amdgcn_sched_barrier(0);
        __builtin_amdgcn_s_barrier();     // protect buf[cur] before next stage
        cur ^= 1;
    }
    #undef STAGE

    float tot = lpart;
    tot += __shfl_xor(tot, 16);
    tot += __shfl_xor(tot, 32);
    float inv = 1.f / fmaxf(tot, 1e-30f);

    u16* ob = x2 + ((size_t)(n * L_SEQ + q0 + r16)) * EMB + h * 64;
    for (int db = 0; db < 4; db++)
        for (int i = 0; i < 4; i++)
            ob[db * 16 + 4 * g + i] = f2bf(o[db][i] * inv);
}

// ---------------- K3: OUT = X2 @ Wout^T + bout  (64x64 tiles, grid 1024) -----
// 4 blocks/CU, 4 waves/block (each wave 32x32 output), counted-vmcnt dbuf.
__global__ __launch_bounds__(256) void outgemm_kernel(const u16* __restrict__ x2,
                                                      const u16* __restrict__ Wb,
                                                      const float* __restrict__ bout,
                                                      float* __restrict__ out) {
    __shared__ __align__(16) u16 As[2][64 * 64];
    __shared__ __align__(16) u16 Bs[2][64 * 64];

    int bid = blockIdx.x;
    int mt = bid & 63, nt = bid >> 6;    // consecutive bids share the B panel
    int m0 = mt * 64, n0 = nt * 64;
    int tid = threadIdx.x;
    int w = tid >> 6, lane = tid & 63;
    int g = lane >> 4, r16 = lane & 15;
    int wr = w >> 1, wc = w & 1;         // wave tile: 32 rows x 32 cols

    float4_ acc[2][2] = {};

    int rs = (w << 3) + (lane >> 3);     // row 0..31 (+32 for half 1)
    int cc = (lane & 7) ^ ((lane >> 3) & 7);

    #define OSTAGE(kb_, b_) do {                                                 \
        int kk_ = (kb_) * 64;                                                    \
        for (int h2 = 0; h2 < 2; h2++) {                                         \
            int r_ = rs + 32 * h2;                                               \
            gload16(x2 + (size_t)(m0 + r_) * EMB + kk_ + cc * 8,                 \
                    (char*)As[b_] + w * 1024 + h2 * 4096);                       \
            gload16(Wb + (size_t)(n0 + r_) * EMB + kk_ + cc * 8,                 \
                    (char*)Bs[b_] + w * 1024 + h2 * 4096);                       \
        }                                                                        \
    } while (0)

    OSTAGE(0, 0);
    int cur = 0;

    for (int kbk = 0; kbk < 16; kbk++) {
        if (kbk < 15) {
            OSTAGE(kbk + 1, cur ^ 1);
            __builtin_amdgcn_sched_barrier(0);
            asm volatile("s_waitcnt vmcnt(4)" ::: "memory");
        } else {
            asm volatile("s_waitcnt vmcnt(0)" ::: "memory");
        }
        __builtin_amdgcn_s_barrier();
        __builtin_amdgcn_sched_barrier(0);

        const char* pa = (const char*)As[cur];
        const char* pb = (const char*)Bs[cur];

        short8 afr[2][2], bfr[2][2];
        for (int sm = 0; sm < 2; sm++)
            for (int ch = 0; ch < 2; ch++) {
                int row = wr * 32 + sm * 16 + r16;
                afr[sm][ch] = *(const short8*)(pa + row * 128 + ((ch * 64 + 16 * g) ^ ((row & 7) << 4)));
            }
        for (int sn = 0; sn < 2; sn++)
            for (int ch = 0; ch < 2; ch++) {
                int row = wc * 32 + sn * 16 + r16;
                bfr[sn][ch] = *(const short8*)(pb + row * 128 + ((ch * 64 + 16 * g) ^ ((row & 7) << 4)));
            }
        __builtin_amdgcn_s_setprio(1);
        for (int sm = 0; sm < 2; sm++)
            for (int sn = 0; sn < 2; sn++) {
                acc[sm][sn] = __builtin_amdgcn_mfma_f32_16x16x32_bf16(afr[sm][0], bfr[sn][0], acc[sm][sn], 0, 0, 0);
                acc[sm][sn] = __builtin_amdgcn_mfma_f32_16x16x32_bf16(afr[sm][1], bfr[sn][1], acc[sm][sn], 0, 0, 0);
            }
        __builtin_amdgcn_s_setprio(0);

        __builtin_amdgcn_sched_barrier(0);
        __builtin_amdgcn_s_barrier();
        cur ^= 1;
    }
    #undef OSTAGE

    for (int sm = 0; sm < 2; sm++)
        for (int sn = 0; sn < 2; sn++) {
            int nn = n0 + wc * 32 + sn * 16 + r16;
            float bv = bout[nn];
            for (int i = 0; i < 4; i++) {
                int mm = m0 + wr * 32 + sm * 16 + 4 * g + i;
                out[(size_t)mm * EMB + nn] = acc[sm][sn][i] + bv;
            }
        }
}

extern "C" void kernel_launch(void* const* d_in, const int* in_sizes, int n_in,
                              void* d_out, int out_size, void* d_ws, size_t ws_size,
                              hipStream_t stream) {
    const float* values = (const float*)d_in[0];
    const float* keys   = (const float*)d_in[1];
    const float* query  = (const float*)d_in[2];
    const int*   mask   = (const int*)d_in[3];
    const float* Wv     = (const float*)d_in[4];
    const float* Wk     = (const float*)d_in[5];
    const float* Wq     = (const float*)d_in[6];
    const float* Wout   = (const float*)d_in[7];
    const float* bout   = (const float*)d_in[8];
    float* out = (float*)d_out;

    char* ws = (char*)d_ws;
    u16* kp  = (u16*)(ws + KP_OFF);
    u16* vpT = (u16*)(ws + VP_OFF);
    u16* x2  = (u16*)(ws + X2_OFF);
    unsigned long long* mpk = (unsigned long long*)(ws + MP_OFF);
    u16* wb  = (u16*)(ws + WB_OFF);

    prep_kernel<<<PREP_TOTAL, 256, 0, stream>>>(mask, mpk, Wout, wb,
                                                keys, Wk, kp, values, Wv, vpT);
    attn_kernel<<<1024, 256, 0, stream>>>(query, Wq, kp, vpT, mpk, x2);
    outgemm_kernel<<<1024, 256, 0, stream>>>(x2, wb, bout, out);
}